// Round 7
// baseline (240.930 us; speedup 1.0000x reference)
//
#include <hip/hip_runtime.h>
#include <stdint.h>

#define B_ 2
#define S_ 2048
#define D_ 1024
#define H_ 16
#define DH_ 64
#define M_ 4096
#define LOG2E 1.44269504088896340736f

typedef __attribute__((ext_vector_type(8))) short short8;
typedef __attribute__((ext_vector_type(4))) float f32x4;
typedef __attribute__((ext_vector_type(16))) float f32x16;

__device__ __forceinline__ unsigned short f2bf(float f) {
  union { float f; uint32_t u; } x; x.f = f;
  uint32_t u = x.u;
  u += 0x7FFFu + ((u >> 16) & 1u);
  return (unsigned short)(u >> 16);
}

__device__ __forceinline__ float bf2f(unsigned short u) {
  union { uint32_t u; float f; } x; x.u = (uint32_t)u << 16; return x.f;
}

__device__ __forceinline__ unsigned int pack_bf(float lo, float hi2) {
  return (unsigned int)f2bf(lo) | ((unsigned int)f2bf(hi2) << 16);
}

__device__ __forceinline__ void gll16(const void* g, void* l) {
  __builtin_amdgcn_global_load_lds(
      (__attribute__((address_space(1))) void*)(g),
      (__attribute__((address_space(3))) void*)(l), 16, 0, 0);
}

// ---- fused prep: hidden f32->bf16 (blocks 0..4095), Wqkv^T (4096..7167),
// ---- Wproj^T (7168..8191) ----
__global__ __launch_bounds__(256) void k_prep(const float* __restrict__ hs,
                                              const float* __restrict__ Wqkv,
                                              const float* __restrict__ Wproj,
                                              unsigned short* __restrict__ hid,
                                              unsigned short* __restrict__ wqkvT,
                                              unsigned short* __restrict__ wprT) {
  __shared__ unsigned short tile[32][33];
  const int id = blockIdx.x;
  if (id < 4096) {
    const int i = id * 256 + threadIdx.x;
    float4 v = reinterpret_cast<const float4*>(hs)[i];
    ushort4 o;
    o.x = f2bf(v.x); o.y = f2bf(v.y); o.z = f2bf(v.z); o.w = f2bf(v.w);
    reinterpret_cast<ushort4*>(hid)[i] = o;
    return;
  }
  const float* W;
  unsigned short* WT;
  int N, i;
  if (id < 7168) { i = id - 4096; W = Wqkv; WT = wqkvT; N = 3072; }
  else           { i = id - 7168; W = Wproj; WT = wprT; N = 1024; }
  const int nb = (N == 3072) ? 96 : 32;
  const int n0 = (i % nb) * 32, k0 = (i / nb) * 32;
  const int tx = threadIdx.x & 31, ty = threadIdx.x >> 5;  // ty 0..7
#pragma unroll
  for (int j = 0; j < 4; j++) {
    int k = ty + j * 8;
    tile[k][tx] = f2bf(W[(long)(k0 + k) * N + n0 + tx]);
  }
  __syncthreads();
#pragma unroll
  for (int j = 0; j < 4; j++) {
    int n = ty + j * 8;
    WT[(long)(n0 + n) * 1024 + k0 + tx] = tile[tx][n];
  }
}

// ---- 128xBN bf16 GEMM, A[M][K], BT[N][K]; MODE 0 = qkv scatter (BN=128),
// ---- MODE 1 = f32 out. BN in {64,128}; warps 2x2 over (128, BN). ----
template <int MODE, int BN>
__global__ __launch_bounds__(256) void k_gemm(
    const unsigned short* __restrict__ A,
    const unsigned short* __restrict__ BT,
    const float* __restrict__ bias,
    void* __restrict__ out0,
    unsigned short* __restrict__ outk,
    unsigned short* __restrict__ outv,
    int M, int N, int K) {
  constexpr int JN = BN / 32;  // 16-col j-tiles per warp
  __shared__ __align__(16) unsigned short lds_a[128 * 32];
  __shared__ __align__(16) unsigned short lds_b[BN * 32];
  const int t = threadIdx.x;
  const int w = t >> 6, l = t & 63;
  const int g = l >> 4, x = l & 15;
  const int wr = w >> 1, wc = w & 1;
  const long m0 = (long)blockIdx.x * 128, n0 = (long)blockIdx.y * BN;

  f32x4 acc[4][JN];
#pragma unroll
  for (int i = 0; i < 4; i++)
#pragma unroll
    for (int j = 0; j < JN; j++) acc[i][j] = (f32x4){0.f, 0.f, 0.f, 0.f};

  const unsigned short* ga = A + (m0 + 16 * w + (l >> 2)) * (long)K + (l & 3) * 8;
  const unsigned short* gb = BT + (n0 + 16 * w + (l >> 2)) * (long)K + (l & 3) * 8;
  unsigned short* la = lds_a + w * 512;
  unsigned short* lb = lds_b + w * 512;

  for (int k0 = 0; k0 < K; k0 += 32) {
    __syncthreads();
    gll16(ga + k0, la);
    gll16(ga + k0 + 64 * (long)K, la + 2048);
    gll16(gb + k0, lb);
    if (BN == 128) gll16(gb + k0 + 64 * (long)K, lb + 2048);
    __syncthreads();
    short8 af[4], bfr[JN];
#pragma unroll
    for (int i = 0; i < 4; i++)
      af[i] = *reinterpret_cast<const short8*>(lds_a + (wr * 64 + i * 16 + x) * 32 + g * 8);
#pragma unroll
    for (int j = 0; j < JN; j++)
      bfr[j] = *reinterpret_cast<const short8*>(
          lds_b + (wc * (BN / 2) + j * 16 + x) * 32 + g * 8);
#pragma unroll
    for (int i = 0; i < 4; i++)
#pragma unroll
      for (int j = 0; j < JN; j++)
        acc[i][j] = __builtin_amdgcn_mfma_f32_16x16x32_bf16(af[i], bfr[j], acc[i][j], 0, 0, 0);
  }

#pragma unroll
  for (int i = 0; i < 4; i++) {
#pragma unroll
    for (int j = 0; j < JN; j++) {
#pragma unroll
      for (int r = 0; r < 4; r++) {
        const long m = m0 + wr * 64 + i * 16 + 4 * g + r;
        const long n = n0 + wc * (BN / 2) + j * 16 + x;
        float v = acc[i][j][r] + bias[n];
        if (MODE == 1) {
          ((float*)out0)[m * N + n] = v;
        } else {
          const int b = (int)(m >> 11), s = (int)(m & 2047);
          const int which = (int)(n >> 10);
          const int rem = (int)(n & 1023);
          const int h = rem >> 6, d = rem & 63;
          const long idx = (((long)(b * H_ + h)) * S_ + s) * DH_ + d;
          unsigned short bv = f2bf(v);
          if (which == 0) ((unsigned short*)out0)[idx] = bv;
          else if (which == 1) outk[idx] = bv;
          else outv[idx] = bv;
        }
      }
    }
  }
}

// ---- V [bh][s][dh] -> VT [bh][dh][s] ----
__global__ __launch_bounds__(256) void k_tr_v(const unsigned short* __restrict__ v,
                                              unsigned short* __restrict__ vt) {
  __shared__ __align__(16) unsigned short tile[64][72];
  const int bh = blockIdx.y;
  const int s0 = blockIdx.x * 64;
  const int t = threadIdx.x;
  const int r = t >> 2;
  const int c = (t & 3) * 16;
  const unsigned short* src = v + ((long)bh * S_ + s0 + r) * DH_ + c;
  *reinterpret_cast<short8*>(&tile[r][c]) = *reinterpret_cast<const short8*>(src);
  *reinterpret_cast<short8*>(&tile[r][c + 8]) = *reinterpret_cast<const short8*>(src + 8);
  __syncthreads();
  unsigned short* dst = vt + ((long)bh * DH_ + r) * S_ + s0 + c;
#pragma unroll
  for (int jj = 0; jj < 2; jj++) {
    short8 o;
#pragma unroll
    for (int j = 0; j < 8; j++) o[j] = (short)tile[c + jj * 8 + j][r];
    *reinterpret_cast<short8*>(dst + jj * 8) = o;
  }
}

// ---- causal flash attention, KV-split, NO LDS: K/V fragments read directly
// from global (L2-resident: K+V+VT per bh = 768 KB; 4 bh per XCD via swizzle).
// No barriers, no staging -> waves fully self-paced; occupancy VGPR-bound.
// Block swizzle: id -> xcd=id&7, bh=4*xcd+((id>>3)&3), sx=id>>5 (bijective);
// sx -> (qc, sp) with nspl(qc)=qc/4+1 splits of <=8 kv-tiles.
// Each split writes unnormalized O-partial (bf16, scaled 2^-m) + (m, l)/row.
__global__ __launch_bounds__(256) void k_attn(const unsigned short* __restrict__ qb_,
                                              const unsigned short* __restrict__ kb,
                                              const unsigned short* __restrict__ vt,
                                              unsigned short* __restrict__ po,
                                              float* __restrict__ pm,
                                              float* __restrict__ pl) {
  const int t0_ = threadIdx.x;
  const int w = t0_ >> 6, l = t0_ & 63;
  const int q32 = l & 31, hi = l >> 5;

  const int id = blockIdx.x;
  const int bh = 4 * (id & 7) + ((id >> 3) & 3);
  const int sx = id >> 5;

  const long kvbase = (long)bh * S_ * DH_;
  const long vtbase = (long)bh * DH_ * S_;
  const float SC = 0.125f * LOG2E;  // scores kept in log2 domain

  // map split index -> (qc, sp)
  int qc = 0, sp = 0;
  {
    int acc = 0;
    for (int q = 0; q < 16; q++) {
      const int ns = (q >> 2) + 1;
      if (sx < acc + ns) { qc = q; sp = sx - acc; break; }
      acc += ns;
    }
  }
  const int nspl = (qc >> 2) + 1;
  const int nt = 2 * qc + 2;
  const int ts = sp * nt / nspl;        // first tile (inclusive)
  const int te = (sp + 1) * nt / nspl;  // last tile (exclusive)

  const int q0w = qc * 128 + 32 * w;
  const int qg = q0w + q32;
  const int te_w = min(te, ((q0w + 31) >> 6) + 1);  // warp's live tile bound
  const long pidx = ((long)(bh * 16 + qc)) * 4 + sp;

  const unsigned short* kbb = kb + kvbase;
  const unsigned short* vtb = vt + vtbase;

  // Q fragments (B-operand): row qg, dh = 16f + 8*hi + j
  short8 qf[4];
#pragma unroll
  for (int f = 0; f < 4; f++)
    qf[f] = *reinterpret_cast<const short8*>(qb_ + kvbase + (long)qg * DH_ + 16 * f + 8 * hi);

  f32x16 oacc[2];
#pragma unroll
  for (int dt = 0; dt < 2; dt++)
#pragma unroll
    for (int r = 0; r < 16; r++) oacc[dt][r] = 0.f;
  float m = -1.0e30f, lown = 0.f;

#pragma unroll 2
  for (int tt = ts; tt < te_w; tt++) {
    const int kv0 = tt * 64;

    // QK^T (swapped): sa[ks][reg] = S^T[kv = 32ks + R(reg,hi)][q = q32]
    // K fragment read straight from global: row kv0+32ks+q32, 16B at 16f+8hi.
    f32x16 sa[2];
#pragma unroll
    for (int ks = 0; ks < 2; ks++) {
#pragma unroll
      for (int r = 0; r < 16; r++) sa[ks][r] = 0.f;
#pragma unroll
      for (int f = 0; f < 4; f++) {
        short8 kf = *reinterpret_cast<const short8*>(
            kbb + (long)(kv0 + 32 * ks + q32) * 64 + 16 * f + 8 * hi);
        sa[ks] = __builtin_amdgcn_mfma_f32_32x32x16_bf16(kf, qf[f], sa[ks], 0, 0, 0);
      }
    }

    float p[32];
#pragma unroll
    for (int ks = 0; ks < 2; ks++)
#pragma unroll
      for (int r = 0; r < 16; r++) p[16 * ks + r] = sa[ks][r] * SC;

    const bool diag = (kv0 + 63 > q0w);
    if (diag) {
#pragma unroll
      for (int ks = 0; ks < 2; ks++)
#pragma unroll
        for (int r = 0; r < 16; r++) {
          const int kvg = kv0 + 32 * ks + (r & 3) + 8 * (r >> 2) + 4 * hi;
          if (kvg > qg) p[16 * ks + r] = -1.0e30f;
        }
    }

    // tile max (in-lane tree + lane^32 partner)
    float mx[16];
#pragma unroll
    for (int r = 0; r < 16; r++) mx[r] = fmaxf(p[r], p[r + 16]);
#pragma unroll
    for (int st = 8; st >= 1; st >>= 1)
#pragma unroll
      for (int r = 0; r < 8; r++)
        if (r < st) mx[r] = fmaxf(mx[r], mx[r + st]);
    float pmax = fmaxf(mx[0], __shfl_xor(mx[0], 32, 64));

    // defer-max rescale (THR = 8 in log2 domain)
    if (__any(pmax > m + 8.0f)) {
      const float mn = fmaxf(m, pmax);
      const float fsc = exp2f(m - mn);
      m = mn;
      lown *= fsc;
#pragma unroll
      for (int r = 0; r < 16; r++) {
        const int rr = (r & 3) + 8 * (r >> 2) + 4 * hi;
        const float fr = __int_as_float(
            __builtin_amdgcn_ds_bpermute(rr << 2, __float_as_int(fsc)));
        oacc[0][r] *= fr;
        oacc[1][r] *= fr;
      }
    }

    // exp (log2 domain)
#pragma unroll
    for (int i = 0; i < 32; i++) p[i] = exp2f(p[i] - m);

    // own-half row sum (partner combined once at end)
    float sm[16];
#pragma unroll
    for (int r = 0; r < 16; r++) sm[r] = p[r] + p[r + 16];
#pragma unroll
    for (int st = 8; st >= 1; st >>= 1)
#pragma unroll
      for (int r = 0; r < 8; r++)
        if (r < st) sm[r] += sm[r + st];
    lown += sm[0];

    // PV: 4 k-steps of 16 kv. A-word j-pair must hold
    // P[q32][kv = 16*s4 + 8*hi + {2j, 2j+1}]; other half via lane^32.
    // V fragment straight from global VT: row 32dt+q32, 16B at kv0+16s4+8hi.
#pragma unroll
    for (int s4 = 0; s4 < 4; s4++) {
      const int bse = 8 * s4;
      unsigned int t0p = pack_bf(p[bse + 0], p[bse + 1]);
      unsigned int t1p = pack_bf(p[bse + 2], p[bse + 3]);
      unsigned int t2p = pack_bf(p[bse + 4], p[bse + 5]);
      unsigned int t3p = pack_bf(p[bse + 6], p[bse + 7]);
      unsigned int t0x = __shfl_xor(t0p, 32, 64);
      unsigned int t1x = __shfl_xor(t1p, 32, 64);
      unsigned int t2x = __shfl_xor(t2p, 32, 64);
      unsigned int t3x = __shfl_xor(t3p, 32, 64);
      union { unsigned int u[4]; short8 s8; } pa;
      pa.u[0] = hi ? t2x : t0p;  // kv +{0,1}
      pa.u[1] = hi ? t3x : t1p;  // kv +{2,3}
      pa.u[2] = hi ? t2p : t0x;  // kv +{4,5}
      pa.u[3] = hi ? t3p : t1x;  // kv +{6,7}
#pragma unroll
      for (int dt = 0; dt < 2; dt++) {
        short8 vf = *reinterpret_cast<const short8*>(
            vtb + (long)(32 * dt + q32) * S_ + kv0 + 16 * s4 + 8 * hi);
        oacc[dt] = __builtin_amdgcn_mfma_f32_32x32x16_bf16(pa.s8, vf, oacc[dt], 0, 0, 0);
      }
    }
  }

  // epilogue: write unnormalized partial O (bf16) + per-row (m, l)
  const float lt = lown + __shfl_xor(lown, 32, 64);
  if (hi == 0) {
    pm[pidx * 128 + 32 * w + q32] = m;
    pl[pidx * 128 + 32 * w + q32] = lt;
  }
  unsigned short* pob = po + pidx * 8192;
#pragma unroll
  for (int r = 0; r < 16; r++) {
    const int rr = (r & 3) + 8 * (r >> 2) + 4 * hi;
    const int row = 32 * w + rr;
#pragma unroll
    for (int dt = 0; dt < 2; dt++)
      pob[row * 64 + 32 * dt + q32] = f2bf(oacc[dt][r]);
  }
}

// ---- combine partials: block (qc, bh); thread t: row = t>>1, 32 cols ----
__global__ __launch_bounds__(256) void k_comb(const unsigned short* __restrict__ po,
                                              const float* __restrict__ pm,
                                              const float* __restrict__ pl,
                                              unsigned short* __restrict__ ao) {
  const int qc = blockIdx.x, bh = blockIdx.y;
  const int b = bh >> 4, h = bh & 15;
  const int nspl = (qc >> 2) + 1;
  const int t = threadIdx.x;
  const int r = t >> 1, c0 = (t & 1) * 32;
  const long pbase = ((long)(bh * 16 + qc)) * 4;

  float mi[4], li[4], wi[4];
  float ms = -3.0e38f;
#pragma unroll
  for (int i = 0; i < 4; i++) {
    if (i < nspl) {
      mi[i] = pm[(pbase + i) * 128 + r];
      li[i] = pl[(pbase + i) * 128 + r];
      ms = fmaxf(ms, mi[i]);
    }
  }
  float wsum = 0.f;
#pragma unroll
  for (int i = 0; i < 4; i++) {
    if (i < nspl) {
      wi[i] = exp2f(mi[i] - ms);
      wsum += wi[i] * li[i];
    }
  }
  float acc[32];
#pragma unroll
  for (int j = 0; j < 32; j++) acc[j] = 0.f;
#pragma unroll
  for (int i = 0; i < 4; i++) {
    if (i < nspl) {
      const unsigned short* src = po + (pbase + i) * 8192 + r * 64 + c0;
#pragma unroll
      for (int v = 0; v < 4; v++) {
        short8 s = *reinterpret_cast<const short8*>(src + v * 8);
#pragma unroll
        for (int j = 0; j < 8; j++)
          acc[v * 8 + j] += wi[i] * bf2f((unsigned short)s[j]);
      }
    }
  }
  const float inv = 1.0f / wsum;
  unsigned short* dst = ao + ((long)b * S_ + qc * 128 + r) * (H_ * DH_) + h * DH_ + c0;
#pragma unroll
  for (int v = 0; v < 4; v++) {
    short8 o;
#pragma unroll
    for (int j = 0; j < 8; j++) o[j] = (short)f2bf(acc[v * 8 + j] * inv);
    *reinterpret_cast<short8*>(dst + v * 8) = o;
  }
}

extern "C" void kernel_launch(void* const* d_in, const int* in_sizes, int n_in,
                              void* d_out, int out_size, void* d_ws, size_t ws_size,
                              hipStream_t stream) {
  (void)in_sizes; (void)n_in; (void)out_size; (void)ws_size;
  const float* hs    = (const float*)d_in[0];
  // d_in[1] = attention_mask: deterministic causal tril, applied analytically.
  const float* Wqkv  = (const float*)d_in[2];
  const float* bqkv  = (const float*)d_in[3];
  const float* Wproj = (const float*)d_in[4];
  const float* bproj = (const float*)d_in[5];
  float* out = (float*)d_out;

  unsigned short* ws    = (unsigned short*)d_ws;
  unsigned short* hid   = ws;                 // 4096*1024
  unsigned short* wqkvT = hid + 4194304;      // 3072*1024
  unsigned short* wprT  = wqkvT + 3145728;    // 1024*1024
  unsigned short* q_b   = wprT + 1048576;     // [bh][s][dh]
  unsigned short* k_b   = q_b + 4194304;
  unsigned short* v_b   = k_b + 4194304;
  unsigned short* vt_b  = v_b + 4194304;      // [bh][dh][s]
  unsigned short* ao    = vt_b + 4194304;     // [b*s][H*DH]
  unsigned short* po    = ao + 4194304;       // [32*16*4][128][64] bf16 partials
  float* pm = (float*)(po + 16777216);        // [32*16*4][128]
  float* pl = pm + 262144;

  k_prep<<<8192, 256, 0, stream>>>(hs, Wqkv, Wproj, hid, wqkvT, wprT);
  k_gemm<0, 128><<<dim3(32, 24), 256, 0, stream>>>(hid, wqkvT, bqkv, (void*)q_b, k_b, v_b,
                                                   4096, 3072, 1024);
  k_tr_v<<<dim3(32, 32), 256, 0, stream>>>(v_b, vt_b);
  k_attn<<<1280, 256, 0, stream>>>(q_b, k_b, vt_b, po, pm, pl);
  k_comb<<<dim3(16, 32), 256, 0, stream>>>(po, pm, pl, ao);
  k_gemm<1, 64><<<dim3(32, 16), 256, 0, stream>>>(ao, wprT, bproj, (void*)out, nullptr, nullptr,
                                                  4096, 1024, 1024);
}

// Round 8
// 221.514 us; speedup vs baseline: 1.0877x; 1.0877x over previous
//
#include <hip/hip_runtime.h>
#include <hip/hip_bf16.h>
#include <stdint.h>

#define B_ 2
#define S_ 2048
#define D_ 1024
#define H_ 16
#define DH_ 64
#define M_ 4096
#define LOG2E 1.44269504088896340736f

typedef __attribute__((ext_vector_type(8))) short short8;
typedef __attribute__((ext_vector_type(4))) float f32x4;
typedef __attribute__((ext_vector_type(16))) float f32x16;

__device__ __forceinline__ unsigned short f2bf(float f) {
  __hip_bfloat16 h = __float2bfloat16(f);  // RNE hardware cvt
  union { __hip_bfloat16 h; unsigned short u; } cv;
  cv.h = h;
  return cv.u;
}

__device__ __forceinline__ unsigned int pack_bf(float lo, float hi2) {
  union { __hip_bfloat162 h; unsigned int u; } cv;
  cv.h = __float22bfloat162_rn(make_float2(lo, hi2));  // v_cvt_pk_bf16_f32
  return cv.u;
}

__device__ __forceinline__ void gll16(const void* g, void* l) {
  __builtin_amdgcn_global_load_lds(
      (__attribute__((address_space(1))) void*)(g),
      (__attribute__((address_space(3))) void*)(l), 16, 0, 0);
}

// ---- fused prep: hidden f32->bf16 (blocks 0..4095), Wqkv^T (4096..7167),
// ---- Wproj^T (7168..8191) ----
__global__ __launch_bounds__(256) void k_prep(const float* __restrict__ hs,
                                              const float* __restrict__ Wqkv,
                                              const float* __restrict__ Wproj,
                                              unsigned short* __restrict__ hid,
                                              unsigned short* __restrict__ wqkvT,
                                              unsigned short* __restrict__ wprT) {
  __shared__ unsigned short tile[32][33];
  const int id = blockIdx.x;
  if (id < 4096) {
    const int i = id * 256 + threadIdx.x;
    float4 v = reinterpret_cast<const float4*>(hs)[i];
    ushort4 o;
    o.x = f2bf(v.x); o.y = f2bf(v.y); o.z = f2bf(v.z); o.w = f2bf(v.w);
    reinterpret_cast<ushort4*>(hid)[i] = o;
    return;
  }
  const float* W;
  unsigned short* WT;
  int N, i;
  if (id < 7168) { i = id - 4096; W = Wqkv; WT = wqkvT; N = 3072; }
  else           { i = id - 7168; W = Wproj; WT = wprT; N = 1024; }
  const int nb = (N == 3072) ? 96 : 32;
  const int n0 = (i % nb) * 32, k0 = (i / nb) * 32;
  const int tx = threadIdx.x & 31, ty = threadIdx.x >> 5;  // ty 0..7
#pragma unroll
  for (int j = 0; j < 4; j++) {
    int k = ty + j * 8;
    tile[k][tx] = f2bf(W[(long)(k0 + k) * N + n0 + tx]);
  }
  __syncthreads();
#pragma unroll
  for (int j = 0; j < 4; j++) {
    int n = ty + j * 8;
    WT[(long)(n0 + n) * 1024 + k0 + tx] = tile[tx][n];
  }
}

// ---- 128xBN bf16 GEMM, A[M][K], BT[N][K]; MODE 0 = qkv scatter (BN=128),
// ---- MODE 1 = f32 out. BN in {64,128}; warps 2x2 over (128, BN). ----
template <int MODE, int BN>
__global__ __launch_bounds__(256) void k_gemm(
    const unsigned short* __restrict__ A,
    const unsigned short* __restrict__ BT,
    const float* __restrict__ bias,
    void* __restrict__ out0,
    unsigned short* __restrict__ outk,
    unsigned short* __restrict__ outv,
    int M, int N, int K) {
  constexpr int JN = BN / 32;  // 16-col j-tiles per warp
  __shared__ __align__(16) unsigned short lds_a[128 * 32];
  __shared__ __align__(16) unsigned short lds_b[BN * 32];
  const int t = threadIdx.x;
  const int w = t >> 6, l = t & 63;
  const int g = l >> 4, x = l & 15;
  const int wr = w >> 1, wc = w & 1;
  const long m0 = (long)blockIdx.x * 128, n0 = (long)blockIdx.y * BN;

  f32x4 acc[4][JN];
#pragma unroll
  for (int i = 0; i < 4; i++)
#pragma unroll
    for (int j = 0; j < JN; j++) acc[i][j] = (f32x4){0.f, 0.f, 0.f, 0.f};

  const unsigned short* ga = A + (m0 + 16 * w + (l >> 2)) * (long)K + (l & 3) * 8;
  const unsigned short* gb = BT + (n0 + 16 * w + (l >> 2)) * (long)K + (l & 3) * 8;
  unsigned short* la = lds_a + w * 512;
  unsigned short* lb = lds_b + w * 512;

  for (int k0 = 0; k0 < K; k0 += 32) {
    __syncthreads();
    gll16(ga + k0, la);
    gll16(ga + k0 + 64 * (long)K, la + 2048);
    gll16(gb + k0, lb);
    if (BN == 128) gll16(gb + k0 + 64 * (long)K, lb + 2048);
    __syncthreads();
    short8 af[4], bfr[JN];
#pragma unroll
    for (int i = 0; i < 4; i++)
      af[i] = *reinterpret_cast<const short8*>(lds_a + (wr * 64 + i * 16 + x) * 32 + g * 8);
#pragma unroll
    for (int j = 0; j < JN; j++)
      bfr[j] = *reinterpret_cast<const short8*>(
          lds_b + (wc * (BN / 2) + j * 16 + x) * 32 + g * 8);
#pragma unroll
    for (int i = 0; i < 4; i++)
#pragma unroll
      for (int j = 0; j < JN; j++)
        acc[i][j] = __builtin_amdgcn_mfma_f32_16x16x32_bf16(af[i], bfr[j], acc[i][j], 0, 0, 0);
  }

#pragma unroll
  for (int i = 0; i < 4; i++) {
#pragma unroll
    for (int j = 0; j < JN; j++) {
#pragma unroll
      for (int r = 0; r < 4; r++) {
        const long m = m0 + wr * 64 + i * 16 + 4 * g + r;
        const long n = n0 + wc * (BN / 2) + j * 16 + x;
        float v = acc[i][j][r] + bias[n];
        if (MODE == 1) {
          ((float*)out0)[m * N + n] = v;
        } else {
          const int b = (int)(m >> 11), s = (int)(m & 2047);
          const int which = (int)(n >> 10);
          const int rem = (int)(n & 1023);
          const int h = rem >> 6, d = rem & 63;
          const long idx = (((long)(b * H_ + h)) * S_ + s) * DH_ + d;
          unsigned short bv = f2bf(v);
          if (which == 0) ((unsigned short*)out0)[idx] = bv;
          else if (which == 1) outk[idx] = bv;
          else outv[idx] = bv;
        }
      }
    }
  }
}

// ---- V [bh][s][dh] -> VT [bh][dh][s] ----
__global__ __launch_bounds__(256) void k_tr_v(const unsigned short* __restrict__ v,
                                              unsigned short* __restrict__ vt) {
  __shared__ __align__(16) unsigned short tile[64][72];
  const int bh = blockIdx.y;
  const int s0 = blockIdx.x * 64;
  const int t = threadIdx.x;
  const int r = t >> 2;
  const int c = (t & 3) * 16;
  const unsigned short* src = v + ((long)bh * S_ + s0 + r) * DH_ + c;
  *reinterpret_cast<short8*>(&tile[r][c]) = *reinterpret_cast<const short8*>(src);
  *reinterpret_cast<short8*>(&tile[r][c + 8]) = *reinterpret_cast<const short8*>(src + 8);
  __syncthreads();
  unsigned short* dst = vt + ((long)bh * DH_ + r) * S_ + s0 + c;
#pragma unroll
  for (int jj = 0; jj < 2; jj++) {
    short8 o;
#pragma unroll
    for (int j = 0; j < 8; j++) o[j] = (short)tile[c + jj * 8 + j][r];
    *reinterpret_cast<short8*>(dst + jj * 8) = o;
  }
}

// ---- causal flash attention, 32x32 MFMA, swapped QK^T, in-register softmax ----
// Grid: 512 one-chunk blocks (128 q-rows each). Bijective id->(bh,c) swizzle:
// co-resident ids r, r+256 get complementary chunks (c, 15-c) -> balanced, and
// each bh's K/V stays on one XCD's L2. K/V tiles LDS-staged, double-buffered,
// XOR-swizzled. P->bf16 PV fragments built fully in-register (HW cvt_pk + 2
// shfl_xor per 16-kv slice).
__global__ __launch_bounds__(256, 1) void k_attn(const unsigned short* __restrict__ qb_,
                                                 const unsigned short* __restrict__ kb,
                                                 const unsigned short* __restrict__ vt,
                                                 unsigned short* __restrict__ attn_out) {
  __shared__ __align__(16) unsigned short lds_k[2][4096];
  __shared__ __align__(16) unsigned short lds_v[2][4096];

  const int t0_ = threadIdx.x;
  const int w = t0_ >> 6, l = t0_ & 63;
  const int q32 = l & 31, hi = l >> 5;
  const int r7 = q32 & 7;
  const int lr = l >> 3, sch = (l & 7) ^ lr;  // staging: pre-swizzled source chunk

  const int id = blockIdx.x;
  const int xcd = id & 7, slot = id >> 3;
  const int bh = xcd + 8 * (slot >> 4);
  const int craw = slot & 15;
  const int qc = (slot & 32) ? craw : (15 - craw);

  const int b = bh >> 4, h = bh & 15;
  const long kvbase = (long)bh * S_ * DH_;
  const long vtbase = (long)bh * DH_ * S_;
  const float SC = 0.125f * LOG2E;  // scores kept in log2 domain

  const int q0p = qc * 128;
  const int q0w = q0p + 32 * w;
  const int qg = q0w + q32;
  const int nt = 2 * qc + 2;

  // Q fragments (B-operand): row qg, dh = 16f + 8*hi + j
  short8 qf[4];
#pragma unroll
  for (int f = 0; f < 4; f++)
    qf[f] = *reinterpret_cast<const short8*>(qb_ + kvbase + (long)qg * DH_ + 16 * f + 8 * hi);

  // stage tile 0 into buf 0
#pragma unroll
  for (int i = 0; i < 2; i++) {
    gll16(kb + kvbase + (long)(16 * w + 8 * i + lr) * DH_ + sch * 8,
          &lds_k[0][w * 1024 + i * 512]);
    gll16(vt + vtbase + (long)(16 * w + 8 * i + lr) * S_ + sch * 8,
          &lds_v[0][w * 1024 + i * 512]);
  }

  f32x16 oacc[2];
#pragma unroll
  for (int dt = 0; dt < 2; dt++)
#pragma unroll
    for (int r = 0; r < 16; r++) oacc[dt][r] = 0.f;
  float m = -1.0e30f, lown = 0.f;

  asm volatile("s_waitcnt vmcnt(0)" ::: "memory");
  __syncthreads();

  for (int tt = 0; tt < nt; tt++) {
    const int kv0 = tt * 64;
    // prefetch next tile into other buffer
    if (tt + 1 < nt) {
      const int nb = (tt + 1) & 1;
      const int kvn = kv0 + 64;
#pragma unroll
      for (int i = 0; i < 2; i++) {
        gll16(kb + kvbase + (long)(kvn + 16 * w + 8 * i + lr) * DH_ + sch * 8,
              &lds_k[nb][w * 1024 + i * 512]);
        gll16(vt + vtbase + (long)(16 * w + 8 * i + lr) * S_ + kvn + sch * 8,
              &lds_v[nb][w * 1024 + i * 512]);
      }
    }

    if (kv0 <= q0w + 31) {  // warp has live rows in this tile
      const unsigned short* lk = lds_k[tt & 1];
      const unsigned short* lv = lds_v[tt & 1];

      // QK^T (swapped): sa[ks][reg] = S^T[kv = 32ks + R(reg,hi)][q = q32]
      f32x16 sa[2];
#pragma unroll
      for (int ks = 0; ks < 2; ks++) {
#pragma unroll
        for (int r = 0; r < 16; r++) sa[ks][r] = 0.f;
#pragma unroll
        for (int f = 0; f < 4; f++) {
          short8 kf = *reinterpret_cast<const short8*>(
              lk + (32 * ks + q32) * 64 + (((2 * f + hi) ^ r7) << 3));
          sa[ks] = __builtin_amdgcn_mfma_f32_32x32x16_bf16(kf, qf[f], sa[ks], 0, 0, 0);
        }
      }

      float p[32];
#pragma unroll
      for (int ks = 0; ks < 2; ks++)
#pragma unroll
        for (int r = 0; r < 16; r++) p[16 * ks + r] = sa[ks][r] * SC;

      const bool diag = (kv0 + 63 > q0w);
      if (diag) {
#pragma unroll
        for (int ks = 0; ks < 2; ks++)
#pragma unroll
          for (int r = 0; r < 16; r++) {
            const int kvg = kv0 + 32 * ks + (r & 3) + 8 * (r >> 2) + 4 * hi;
            if (kvg > qg) p[16 * ks + r] = -1.0e30f;
          }
      }

      // tile max (in-lane tree + lane^32 partner)
      float mx[16];
#pragma unroll
      for (int r = 0; r < 16; r++) mx[r] = fmaxf(p[r], p[r + 16]);
#pragma unroll
      for (int st = 8; st >= 1; st >>= 1)
#pragma unroll
        for (int r = 0; r < 8; r++)
          if (r < st) mx[r] = fmaxf(mx[r], mx[r + st]);
      float pmax = fmaxf(mx[0], __shfl_xor(mx[0], 32, 64));

      // defer-max rescale (THR = 8 in log2 domain)
      if (__any(pmax > m + 8.0f)) {
        const float mn = fmaxf(m, pmax);
        const float fsc = exp2f(m - mn);
        m = mn;
        lown *= fsc;
#pragma unroll
        for (int r = 0; r < 16; r++) {
          const int rr = (r & 3) + 8 * (r >> 2) + 4 * hi;
          const float fr = __int_as_float(
              __builtin_amdgcn_ds_bpermute(rr << 2, __float_as_int(fsc)));
          oacc[0][r] *= fr;
          oacc[1][r] *= fr;
        }
      }

      // exp (log2 domain)
#pragma unroll
      for (int i = 0; i < 32; i++) p[i] = exp2f(p[i] - m);

      // own-half row sum (partner combined once at end)
      float sm[16];
#pragma unroll
      for (int r = 0; r < 16; r++) sm[r] = p[r] + p[r + 16];
#pragma unroll
      for (int st = 8; st >= 1; st >>= 1)
#pragma unroll
        for (int r = 0; r < 8; r++)
          if (r < st) sm[r] += sm[r + st];
      lown += sm[0];

      // PV: 4 k-steps of 16 kv. A-word j-pair must hold
      // P[q32][kv = 16*s4 + 8*hi + {2j, 2j+1}]. Each half needs only 2 of the
      // partner's packed words -> pre-select the send value, 2 shfls not 4:
      //   s0 = hi ? t0 : t2  ->  x0 = (hi ? t2x-recv : t0x-recv)
      //   hi=0: x0 = partner's t0 (u[2]); hi=1: x0 = partner's t2 (u[0]).
#pragma unroll
      for (int s4 = 0; s4 < 4; s4++) {
        const int bse = 8 * s4;
        unsigned int t0p = pack_bf(p[bse + 0], p[bse + 1]);
        unsigned int t1p = pack_bf(p[bse + 2], p[bse + 3]);
        unsigned int t2p = pack_bf(p[bse + 4], p[bse + 5]);
        unsigned int t3p = pack_bf(p[bse + 6], p[bse + 7]);
        unsigned int s0 = hi ? t0p : t2p;
        unsigned int s1 = hi ? t1p : t3p;
        unsigned int x0 = __shfl_xor(s0, 32, 64);
        unsigned int x1 = __shfl_xor(s1, 32, 64);
        union { unsigned int u[4]; short8 s8; } pa;
        pa.u[0] = hi ? x0 : t0p;   // kv +{0,1}
        pa.u[1] = hi ? x1 : t1p;   // kv +{2,3}
        pa.u[2] = hi ? t2p : x0;   // kv +{4,5}
        pa.u[3] = hi ? t3p : x1;   // kv +{6,7}
#pragma unroll
        for (int dt = 0; dt < 2; dt++) {
          short8 vf = *reinterpret_cast<const short8*>(
              lv + (32 * dt + q32) * 64 + (((2 * s4 + hi) ^ r7) << 3));
          oacc[dt] = __builtin_amdgcn_mfma_f32_32x32x16_bf16(pa.s8, vf, oacc[dt], 0, 0, 0);
        }
      }
    }

    asm volatile("s_waitcnt vmcnt(0)" ::: "memory");
    __syncthreads();
  }

  // epilogue: combine partner half, normalize, store
  const float lt = lown + __shfl_xor(lown, 32, 64);
  const float linv = 1.0f / lt;
#pragma unroll
  for (int r = 0; r < 16; r++) {
    const int rr = (r & 3) + 8 * (r >> 2) + 4 * hi;
    const float li = __int_as_float(
        __builtin_amdgcn_ds_bpermute(rr << 2, __float_as_int(linv)));
    const long row = (long)b * S_ + q0w + rr;
#pragma unroll
    for (int dt = 0; dt < 2; dt++)
      attn_out[row * (H_ * DH_) + h * DH_ + 32 * dt + q32] = f2bf(oacc[dt][r] * li);
  }
}

extern "C" void kernel_launch(void* const* d_in, const int* in_sizes, int n_in,
                              void* d_out, int out_size, void* d_ws, size_t ws_size,
                              hipStream_t stream) {
  (void)in_sizes; (void)n_in; (void)out_size; (void)ws_size;
  const float* hs    = (const float*)d_in[0];
  // d_in[1] = attention_mask: deterministic causal tril, applied analytically.
  const float* Wqkv  = (const float*)d_in[2];
  const float* bqkv  = (const float*)d_in[3];
  const float* Wproj = (const float*)d_in[4];
  const float* bproj = (const float*)d_in[5];
  float* out = (float*)d_out;

  unsigned short* ws    = (unsigned short*)d_ws;
  unsigned short* hid   = ws;                 // 4096*1024
  unsigned short* wqkvT = hid + 4194304;      // 3072*1024
  unsigned short* wprT  = wqkvT + 3145728;    // 1024*1024
  unsigned short* q_b   = wprT + 1048576;     // [bh][s][dh]
  unsigned short* k_b   = q_b + 4194304;
  unsigned short* v_b   = k_b + 4194304;
  unsigned short* vt_b  = v_b + 4194304;      // [bh][dh][s]
  unsigned short* ao    = vt_b + 4194304;     // [b*s][H*DH]

  k_prep<<<8192, 256, 0, stream>>>(hs, Wqkv, Wproj, hid, wqkvT, wprT);
  k_gemm<0, 128><<<dim3(32, 24), 256, 0, stream>>>(hid, wqkvT, bqkv, (void*)q_b, k_b, v_b,
                                                   4096, 3072, 1024);
  k_tr_v<<<dim3(32, 32), 256, 0, stream>>>(v_b, vt_b);
  k_attn<<<512, 256, 0, stream>>>(q_b, k_b, vt_b, ao);
  k_gemm<1, 64><<<dim3(32, 16), 256, 0, stream>>>(ao, wprT, bproj, (void*)out, nullptr, nullptr,
                                                  4096, 1024, 1024);
}

// Round 9
// 212.819 us; speedup vs baseline: 1.1321x; 1.0409x over previous
//
#include <hip/hip_runtime.h>
#include <hip/hip_bf16.h>
#include <stdint.h>

#define B_ 2
#define S_ 2048
#define D_ 1024
#define H_ 16
#define DH_ 64
#define M_ 4096
#define LOG2E 1.44269504088896340736f

typedef __attribute__((ext_vector_type(8))) short short8;
typedef __attribute__((ext_vector_type(4))) float f32x4;
typedef __attribute__((ext_vector_type(16))) float f32x16;

__device__ __forceinline__ unsigned short f2bf(float f) {
  __hip_bfloat16 h = __float2bfloat16(f);  // RNE hardware cvt
  union { __hip_bfloat16 h; unsigned short u; } cv;
  cv.h = h;
  return cv.u;
}

__device__ __forceinline__ unsigned int pack_bf(float lo, float hi2) {
  union { __hip_bfloat162 h; unsigned int u; } cv;
  cv.h = __float22bfloat162_rn(make_float2(lo, hi2));  // v_cvt_pk_bf16_f32
  return cv.u;
}

__device__ __forceinline__ void gll16(const void* g, void* l) {
  __builtin_amdgcn_global_load_lds(
      (__attribute__((address_space(1))) void*)(g),
      (__attribute__((address_space(3))) void*)(l), 16, 0, 0);
}

// ---- fused prep: hidden f32->bf16 (blocks 0..4095), Wqkv^T (4096..7167),
// ---- Wproj^T (7168..8191) ----
__global__ __launch_bounds__(256) void k_prep(const float* __restrict__ hs,
                                              const float* __restrict__ Wqkv,
                                              const float* __restrict__ Wproj,
                                              unsigned short* __restrict__ hid,
                                              unsigned short* __restrict__ wqkvT,
                                              unsigned short* __restrict__ wprT) {
  __shared__ unsigned short tile[32][33];
  const int id = blockIdx.x;
  if (id < 4096) {
    const int i = id * 256 + threadIdx.x;
    float4 v = reinterpret_cast<const float4*>(hs)[i];
    ushort4 o;
    o.x = f2bf(v.x); o.y = f2bf(v.y); o.z = f2bf(v.z); o.w = f2bf(v.w);
    reinterpret_cast<ushort4*>(hid)[i] = o;
    return;
  }
  const float* W;
  unsigned short* WT;
  int N, i;
  if (id < 7168) { i = id - 4096; W = Wqkv; WT = wqkvT; N = 3072; }
  else           { i = id - 7168; W = Wproj; WT = wprT; N = 1024; }
  const int nb = (N == 3072) ? 96 : 32;
  const int n0 = (i % nb) * 32, k0 = (i / nb) * 32;
  const int tx = threadIdx.x & 31, ty = threadIdx.x >> 5;  // ty 0..7
#pragma unroll
  for (int j = 0; j < 4; j++) {
    int k = ty + j * 8;
    tile[k][tx] = f2bf(W[(long)(k0 + k) * N + n0 + tx]);
  }
  __syncthreads();
#pragma unroll
  for (int j = 0; j < 4; j++) {
    int n = ty + j * 8;
    WT[(long)(n0 + n) * 1024 + k0 + tx] = tile[tx][n];
  }
}

// ---- 128xBN bf16 GEMM, 2-phase double-buffered (stage-early). A[M][K],
// ---- BT[N][K]; MODE 0 = qkv scatter (BN=128), MODE 1 = f32 out. ----
template <int MODE, int BN>
__global__ __launch_bounds__(256) void k_gemm(
    const unsigned short* __restrict__ A,
    const unsigned short* __restrict__ BT,
    const float* __restrict__ bias,
    void* __restrict__ out0,
    unsigned short* __restrict__ outk,
    unsigned short* __restrict__ outv,
    int M, int N, int K) {
  constexpr int JN = BN / 32;  // 16-col j-tiles per warp
  __shared__ __align__(16) unsigned short lds_a[2][128 * 32];
  __shared__ __align__(16) unsigned short lds_b[2][BN * 32];
  const int t = threadIdx.x;
  const int w = t >> 6, l = t & 63;
  const int g = l >> 4, x = l & 15;
  const int wr = w >> 1, wc = w & 1;
  const long m0 = (long)blockIdx.x * 128, n0 = (long)blockIdx.y * BN;

  f32x4 acc[4][JN];
#pragma unroll
  for (int i = 0; i < 4; i++)
#pragma unroll
    for (int j = 0; j < JN; j++) acc[i][j] = (f32x4){0.f, 0.f, 0.f, 0.f};

  const unsigned short* ga = A + (m0 + 16 * w + (l >> 2)) * (long)K + (l & 3) * 8;
  const unsigned short* gb = BT + (n0 + 16 * w + (l >> 2)) * (long)K + (l & 3) * 8;

  auto stage = [&](int nb, int k0) {
    unsigned short* la = lds_a[nb] + w * 512;
    unsigned short* lb = lds_b[nb] + w * 512;
    gll16(ga + k0, la);
    gll16(ga + k0 + 64 * (long)K, la + 2048);
    gll16(gb + k0, lb);
    if (BN == 128) gll16(gb + k0 + 64 * (long)K, lb + 2048);
  };

  stage(0, 0);
  asm volatile("s_waitcnt vmcnt(0)" ::: "memory");
  __syncthreads();

  const int nit = K >> 5;
  for (int it = 0; it < nit; it++) {
    const int cur = it & 1;
    if (it + 1 < nit) stage(cur ^ 1, (it + 1) << 5);  // issue-early prefetch
    short8 af[4], bfr[JN];
#pragma unroll
    for (int i = 0; i < 4; i++)
      af[i] = *reinterpret_cast<const short8*>(
          lds_a[cur] + (wr * 64 + i * 16 + x) * 32 + g * 8);
#pragma unroll
    for (int j = 0; j < JN; j++)
      bfr[j] = *reinterpret_cast<const short8*>(
          lds_b[cur] + (wc * (BN / 2) + j * 16 + x) * 32 + g * 8);
#pragma unroll
    for (int i = 0; i < 4; i++)
#pragma unroll
      for (int j = 0; j < JN; j++)
        acc[i][j] = __builtin_amdgcn_mfma_f32_16x16x32_bf16(af[i], bfr[j], acc[i][j], 0, 0, 0);
    asm volatile("s_waitcnt vmcnt(0)" ::: "memory");
    __syncthreads();
  }

#pragma unroll
  for (int i = 0; i < 4; i++) {
#pragma unroll
    for (int j = 0; j < JN; j++) {
#pragma unroll
      for (int r = 0; r < 4; r++) {
        const long m = m0 + wr * 64 + i * 16 + 4 * g + r;
        const long n = n0 + wc * (BN / 2) + j * 16 + x;
        float v = acc[i][j][r] + bias[n];
        if (MODE == 1) {
          ((float*)out0)[m * N + n] = v;
        } else {
          const int b = (int)(m >> 11), s = (int)(m & 2047);
          const int which = (int)(n >> 10);
          const int rem = (int)(n & 1023);
          const int h = rem >> 6, d = rem & 63;
          const long idx = (((long)(b * H_ + h)) * S_ + s) * DH_ + d;
          unsigned short bv = f2bf(v);
          if (which == 0) ((unsigned short*)out0)[idx] = bv;
          else if (which == 1) outk[idx] = bv;
          else outv[idx] = bv;
        }
      }
    }
  }
}

// ---- V [bh][s][dh] -> VT [bh][dh][s] ----
__global__ __launch_bounds__(256) void k_tr_v(const unsigned short* __restrict__ v,
                                              unsigned short* __restrict__ vt) {
  __shared__ __align__(16) unsigned short tile[64][72];
  const int bh = blockIdx.y;
  const int s0 = blockIdx.x * 64;
  const int t = threadIdx.x;
  const int r = t >> 2;
  const int c = (t & 3) * 16;
  const unsigned short* src = v + ((long)bh * S_ + s0 + r) * DH_ + c;
  *reinterpret_cast<short8*>(&tile[r][c]) = *reinterpret_cast<const short8*>(src);
  *reinterpret_cast<short8*>(&tile[r][c + 8]) = *reinterpret_cast<const short8*>(src + 8);
  __syncthreads();
  unsigned short* dst = vt + ((long)bh * DH_ + r) * S_ + s0 + c;
#pragma unroll
  for (int jj = 0; jj < 2; jj++) {
    short8 o;
#pragma unroll
    for (int j = 0; j < 8; j++) o[j] = (short)tile[c + jj * 8 + j][r];
    *reinterpret_cast<short8*>(dst + jj * 8) = o;
  }
}

// ---- causal flash attention, KVBLK=128, 32x32 MFMA, swapped QK^T ----
// Grid: 512 one-chunk blocks (QBLK=128 q-rows). Bijective id->(bh,qc) swizzle:
// co-resident ids r, r+256 get complementary chunks (qc, 15-qc); per-block
// tiles = qc+1 (pair sums 17). K tile [128][64] swizzled ^(row&7); V tile
// [64][128] swizzled ^(row&15) (2-way, free). Double-buffered, stage-early.
__global__ __launch_bounds__(256, 1) void k_attn(const unsigned short* __restrict__ qb_,
                                                 const unsigned short* __restrict__ kb,
                                                 const unsigned short* __restrict__ vt,
                                                 unsigned short* __restrict__ attn_out) {
  __shared__ __align__(16) unsigned short lds_k[2][8192];  // [128 kv][64 dh]
  __shared__ __align__(16) unsigned short lds_v[2][8192];  // [64 dh][128 kv]

  const int t0_ = threadIdx.x;
  const int w = t0_ >> 6, l = t0_ & 63;
  const int q32 = l & 31, hi = l >> 5;
  const int r7 = q32 & 7;
  const int r15 = q32 & 15;
  const int lr = l >> 3, sch = (l & 7) ^ lr;   // K staging source chunk
  const int lv4 = l >> 4;                      // V staging row-within-4

  const int id = blockIdx.x;
  const int xcd = id & 7, slot = id >> 3;
  const int bh = xcd + 8 * (slot >> 4);
  const int craw = slot & 15;
  const int qc = (slot & 32) ? craw : (15 - craw);

  const int b = bh >> 4, h = bh & 15;
  const long kvbase = (long)bh * S_ * DH_;
  const long vtbase = (long)bh * DH_ * S_;
  const float SC = 0.125f * LOG2E;  // scores kept in log2 domain

  const int q0w = qc * 128 + 32 * w;
  const int qg = q0w + q32;
  const int nt = qc + 1;

  const unsigned short* kbb = kb + kvbase;
  const unsigned short* vtb = vt + vtbase;

  // stage one 128-kv tile (K: 4 gll16 of 8 rows; V: 4 gll16 of 4 dh-rows)
  auto stage = [&](int nb, int kv0) {
#pragma unroll
    for (int i = 0; i < 4; i++) {
      const int R0 = 32 * w + 8 * i;
      gll16(kbb + (long)(kv0 + R0 + lr) * 64 + sch * 8, &lds_k[nb][R0 * 64]);
      const int V0 = 16 * w + 4 * i;
      const int svch = (l & 15) ^ (4 * i + lv4);
      gll16(vtb + (long)(V0 + lv4) * S_ + kv0 + svch * 8, &lds_v[nb][V0 * 128]);
    }
  };

  // Q fragments (B-operand): row qg, dh = 16f + 8*hi + j
  short8 qf[4];
#pragma unroll
  for (int f = 0; f < 4; f++)
    qf[f] = *reinterpret_cast<const short8*>(qb_ + kvbase + (long)qg * DH_ + 16 * f + 8 * hi);

  stage(0, 0);

  f32x16 oacc[2];
#pragma unroll
  for (int dt = 0; dt < 2; dt++)
#pragma unroll
    for (int r = 0; r < 16; r++) oacc[dt][r] = 0.f;
  float m = -1.0e30f, lown = 0.f;

  asm volatile("s_waitcnt vmcnt(0)" ::: "memory");
  __syncthreads();

  for (int tt = 0; tt < nt; tt++) {
    const int kv0 = tt << 7;
    if (tt + 1 < nt) stage((tt + 1) & 1, kv0 + 128);  // issue-early prefetch

    const unsigned short* lk = lds_k[tt & 1];
    const unsigned short* lv = lds_v[tt & 1];

    // QK^T (swapped): p[16ks+r] = S^T[kv = 32ks + R(r,hi)][q = q32] * SC
    float p[64];
    const bool diag = (tt == nt - 1);
#pragma unroll
    for (int ks = 0; ks < 4; ks++) {
      f32x16 sa;
#pragma unroll
      for (int r = 0; r < 16; r++) sa[r] = 0.f;
#pragma unroll
      for (int f = 0; f < 4; f++) {
        short8 kf = *reinterpret_cast<const short8*>(
            lk + (32 * ks + q32) * 64 + (((2 * f + hi) ^ r7) << 3));
        sa = __builtin_amdgcn_mfma_f32_32x32x16_bf16(kf, qf[f], sa, 0, 0, 0);
      }
#pragma unroll
      for (int r = 0; r < 16; r++) {
        float s = sa[r] * SC;
        if (diag) {
          const int kvg = kv0 + 32 * ks + (r & 3) + 8 * (r >> 2) + 4 * hi;
          if (kvg > qg) s = -1.0e30f;
        }
        p[16 * ks + r] = s;
      }
    }

    // tile max (in-lane tree + lane^32 partner)
    float mx[16];
#pragma unroll
    for (int r = 0; r < 16; r++)
      mx[r] = fmaxf(fmaxf(p[r], p[r + 16]), fmaxf(p[r + 32], p[r + 48]));
#pragma unroll
    for (int st = 8; st >= 1; st >>= 1)
#pragma unroll
      for (int r = 0; r < 8; r++)
        if (r < st) mx[r] = fmaxf(mx[r], mx[r + st]);
    float pmax = fmaxf(mx[0], __shfl_xor(mx[0], 32, 64));

    // defer-max rescale (THR = 8 in log2 domain)
    if (__any(pmax > m + 8.0f)) {
      const float mn = fmaxf(m, pmax);
      const float fsc = exp2f(m - mn);
      m = mn;
      lown *= fsc;
#pragma unroll
      for (int r = 0; r < 16; r++) {
        const int rr = (r & 3) + 8 * (r >> 2) + 4 * hi;
        const float fr = __int_as_float(
            __builtin_amdgcn_ds_bpermute(rr << 2, __float_as_int(fsc)));
        oacc[0][r] *= fr;
        oacc[1][r] *= fr;
      }
    }

    // exp (log2 domain)
#pragma unroll
    for (int i = 0; i < 64; i++) p[i] = exp2f(p[i] - m);

    // own-half row sum (partner combined once at end)
    float sm[16];
#pragma unroll
    for (int r = 0; r < 16; r++)
      sm[r] = (p[r] + p[r + 16]) + (p[r + 32] + p[r + 48]);
#pragma unroll
    for (int st = 8; st >= 1; st >>= 1)
#pragma unroll
      for (int r = 0; r < 8; r++)
        if (r < st) sm[r] += sm[r + st];
    lown += sm[0];

    // PV: 8 k-steps of 16 kv. p[8*s4+j] -> kv = 16*s4 + (j&3) + 8*(j>>2) + 4hi.
    // A-word pair holds P[q32][kv = 16*s4 + 8*hi + {2j,2j+1}]; 2 shfls/step.
#pragma unroll
    for (int s4 = 0; s4 < 8; s4++) {
      const int bse = 8 * s4;
      unsigned int t0p = pack_bf(p[bse + 0], p[bse + 1]);
      unsigned int t1p = pack_bf(p[bse + 2], p[bse + 3]);
      unsigned int t2p = pack_bf(p[bse + 4], p[bse + 5]);
      unsigned int t3p = pack_bf(p[bse + 6], p[bse + 7]);
      unsigned int s0 = hi ? t0p : t2p;
      unsigned int s1 = hi ? t1p : t3p;
      unsigned int x0 = __shfl_xor(s0, 32, 64);
      unsigned int x1 = __shfl_xor(s1, 32, 64);
      union { unsigned int u[4]; short8 s8; } pa;
      pa.u[0] = hi ? x0 : t0p;   // kv +{0,1}
      pa.u[1] = hi ? x1 : t1p;   // kv +{2,3}
      pa.u[2] = hi ? t2p : x0;   // kv +{4,5}
      pa.u[3] = hi ? t3p : x1;   // kv +{6,7}
#pragma unroll
      for (int dt = 0; dt < 2; dt++) {
        short8 vf = *reinterpret_cast<const short8*>(
            lv + (32 * dt + q32) * 128 + (((2 * s4 + hi) ^ r15) << 3));
        oacc[dt] = __builtin_amdgcn_mfma_f32_32x32x16_bf16(pa.s8, vf, oacc[dt], 0, 0, 0);
      }
    }

    asm volatile("s_waitcnt vmcnt(0)" ::: "memory");
    __syncthreads();
  }

  // epilogue: combine partner half, normalize, store
  const float lt = lown + __shfl_xor(lown, 32, 64);
  const float linv = 1.0f / lt;
#pragma unroll
  for (int r = 0; r < 16; r++) {
    const int rr = (r & 3) + 8 * (r >> 2) + 4 * hi;
    const float li = __int_as_float(
        __builtin_amdgcn_ds_bpermute(rr << 2, __float_as_int(linv)));
    const long row = (long)b * S_ + q0w + rr;
#pragma unroll
    for (int dt = 0; dt < 2; dt++)
      attn_out[row * (H_ * DH_) + h * DH_ + 32 * dt + q32] = f2bf(oacc[dt][r] * li);
  }
}

extern "C" void kernel_launch(void* const* d_in, const int* in_sizes, int n_in,
                              void* d_out, int out_size, void* d_ws, size_t ws_size,
                              hipStream_t stream) {
  (void)in_sizes; (void)n_in; (void)out_size; (void)ws_size;
  const float* hs    = (const float*)d_in[0];
  // d_in[1] = attention_mask: deterministic causal tril, applied analytically.
  const float* Wqkv  = (const float*)d_in[2];
  const float* bqkv  = (const float*)d_in[3];
  const float* Wproj = (const float*)d_in[4];
  const float* bproj = (const float*)d_in[5];
  float* out = (float*)d_out;

  unsigned short* ws    = (unsigned short*)d_ws;
  unsigned short* hid   = ws;                 // 4096*1024
  unsigned short* wqkvT = hid + 4194304;      // 3072*1024
  unsigned short* wprT  = wqkvT + 3145728;    // 1024*1024
  unsigned short* q_b   = wprT + 1048576;     // [bh][s][dh]
  unsigned short* k_b   = q_b + 4194304;
  unsigned short* v_b   = k_b + 4194304;
  unsigned short* vt_b  = v_b + 4194304;      // [bh][dh][s]
  unsigned short* ao    = vt_b + 4194304;     // [b*s][H*DH]

  k_prep<<<8192, 256, 0, stream>>>(hs, Wqkv, Wproj, hid, wqkvT, wprT);
  k_gemm<0, 128><<<dim3(32, 24), 256, 0, stream>>>(hid, wqkvT, bqkv, (void*)q_b, k_b, v_b,
                                                   4096, 3072, 1024);
  k_tr_v<<<dim3(32, 32), 256, 0, stream>>>(v_b, vt_b);
  k_attn<<<512, 256, 0, stream>>>(q_b, k_b, vt_b, ao);
  k_gemm<1, 64><<<dim3(32, 16), 256, 0, stream>>>(ao, wprT, bproj, (void*)out, nullptr, nullptr,
                                                  4096, 1024, 1024);
}

// Round 10
// 202.612 us; speedup vs baseline: 1.1891x; 1.0504x over previous
//
#include <hip/hip_runtime.h>
#include <hip/hip_bf16.h>
#include <stdint.h>

#define B_ 2
#define S_ 2048
#define D_ 1024
#define H_ 16
#define DH_ 64
#define M_ 4096
#define LOG2E 1.44269504088896340736f

typedef __attribute__((ext_vector_type(8))) short short8;
typedef __attribute__((ext_vector_type(4))) float f32x4;
typedef __attribute__((ext_vector_type(16))) float f32x16;

__device__ __forceinline__ unsigned short f2bf(float f) {
  __hip_bfloat16 h = __float2bfloat16(f);  // RNE hardware cvt
  union { __hip_bfloat16 h; unsigned short u; } cv;
  cv.h = h;
  return cv.u;
}

__device__ __forceinline__ float bf2f(unsigned short u) {
  union { uint32_t u; float f; } x; x.u = (uint32_t)u << 16; return x.f;
}

__device__ __forceinline__ unsigned int pack_bf(float lo, float hi2) {
  union { __hip_bfloat162 h; unsigned int u; } cv;
  cv.h = __float22bfloat162_rn(make_float2(lo, hi2));  // v_cvt_pk_bf16_f32
  return cv.u;
}

__device__ __forceinline__ void gll16(const void* g, void* l) {
  __builtin_amdgcn_global_load_lds(
      (__attribute__((address_space(1))) void*)(g),
      (__attribute__((address_space(3))) void*)(l), 16, 0, 0);
}

// ---- fused prep: hidden f32->bf16 (blocks 0..4095), Wqkv^T (4096..7167),
// ---- Wproj^T (7168..8191) ----
__global__ __launch_bounds__(256) void k_prep(const float* __restrict__ hs,
                                              const float* __restrict__ Wqkv,
                                              const float* __restrict__ Wproj,
                                              unsigned short* __restrict__ hid,
                                              unsigned short* __restrict__ wqkvT,
                                              unsigned short* __restrict__ wprT) {
  __shared__ unsigned short tile[32][33];
  const int id = blockIdx.x;
  if (id < 4096) {
    const int i = id * 256 + threadIdx.x;
    float4 v = reinterpret_cast<const float4*>(hs)[i];
    ushort4 o;
    o.x = f2bf(v.x); o.y = f2bf(v.y); o.z = f2bf(v.z); o.w = f2bf(v.w);
    reinterpret_cast<ushort4*>(hid)[i] = o;
    return;
  }
  const float* W;
  unsigned short* WT;
  int N, i;
  if (id < 7168) { i = id - 4096; W = Wqkv; WT = wqkvT; N = 3072; }
  else           { i = id - 7168; W = Wproj; WT = wprT; N = 1024; }
  const int nb = (N == 3072) ? 96 : 32;
  const int n0 = (i % nb) * 32, k0 = (i / nb) * 32;
  const int tx = threadIdx.x & 31, ty = threadIdx.x >> 5;  // ty 0..7
#pragma unroll
  for (int j = 0; j < 4; j++) {
    int k = ty + j * 8;
    tile[k][tx] = f2bf(W[(long)(k0 + k) * N + n0 + tx]);
  }
  __syncthreads();
#pragma unroll
  for (int j = 0; j < 4; j++) {
    int n = ty + j * 8;
    WT[(long)(n0 + n) * 1024 + k0 + tx] = tile[tx][n];
  }
}

// ---- 128xBN bf16 GEMM, 2-phase double-buffered (stage-early). A[M][K],
// ---- BT[N][K]; MODE 0 = qkv scatter (BN=128), MODE 1 = f32 out. ----
template <int MODE, int BN>
__global__ __launch_bounds__(256) void k_gemm(
    const unsigned short* __restrict__ A,
    const unsigned short* __restrict__ BT,
    const float* __restrict__ bias,
    void* __restrict__ out0,
    unsigned short* __restrict__ outk,
    unsigned short* __restrict__ outv,
    int M, int N, int K) {
  constexpr int JN = BN / 32;  // 16-col j-tiles per warp
  __shared__ __align__(16) unsigned short lds_a[2][128 * 32];
  __shared__ __align__(16) unsigned short lds_b[2][BN * 32];
  const int t = threadIdx.x;
  const int w = t >> 6, l = t & 63;
  const int g = l >> 4, x = l & 15;
  const int wr = w >> 1, wc = w & 1;
  const long m0 = (long)blockIdx.x * 128, n0 = (long)blockIdx.y * BN;

  f32x4 acc[4][JN];
#pragma unroll
  for (int i = 0; i < 4; i++)
#pragma unroll
    for (int j = 0; j < JN; j++) acc[i][j] = (f32x4){0.f, 0.f, 0.f, 0.f};

  const unsigned short* ga = A + (m0 + 16 * w + (l >> 2)) * (long)K + (l & 3) * 8;
  const unsigned short* gb = BT + (n0 + 16 * w + (l >> 2)) * (long)K + (l & 3) * 8;

  auto stage = [&](int nb, int k0) {
    unsigned short* la = lds_a[nb] + w * 512;
    unsigned short* lb = lds_b[nb] + w * 512;
    gll16(ga + k0, la);
    gll16(ga + k0 + 64 * (long)K, la + 2048);
    gll16(gb + k0, lb);
    if (BN == 128) gll16(gb + k0 + 64 * (long)K, lb + 2048);
  };

  stage(0, 0);
  asm volatile("s_waitcnt vmcnt(0)" ::: "memory");
  __syncthreads();

  const int nit = K >> 5;
  for (int it = 0; it < nit; it++) {
    const int cur = it & 1;
    if (it + 1 < nit) stage(cur ^ 1, (it + 1) << 5);  // issue-early prefetch
    short8 af[4], bfr[JN];
#pragma unroll
    for (int i = 0; i < 4; i++)
      af[i] = *reinterpret_cast<const short8*>(
          lds_a[cur] + (wr * 64 + i * 16 + x) * 32 + g * 8);
#pragma unroll
    for (int j = 0; j < JN; j++)
      bfr[j] = *reinterpret_cast<const short8*>(
          lds_b[cur] + (wc * (BN / 2) + j * 16 + x) * 32 + g * 8);
#pragma unroll
    for (int i = 0; i < 4; i++)
#pragma unroll
      for (int j = 0; j < JN; j++)
        acc[i][j] = __builtin_amdgcn_mfma_f32_16x16x32_bf16(af[i], bfr[j], acc[i][j], 0, 0, 0);
    asm volatile("s_waitcnt vmcnt(0)" ::: "memory");
    __syncthreads();
  }

#pragma unroll
  for (int i = 0; i < 4; i++) {
#pragma unroll
    for (int j = 0; j < JN; j++) {
#pragma unroll
      for (int r = 0; r < 4; r++) {
        const long m = m0 + wr * 64 + i * 16 + 4 * g + r;
        const long n = n0 + wc * (BN / 2) + j * 16 + x;
        float v = acc[i][j][r] + bias[n];
        if (MODE == 1) {
          ((float*)out0)[m * N + n] = v;
        } else {
          const int b = (int)(m >> 11), s = (int)(m & 2047);
          const int which = (int)(n >> 10);
          const int rem = (int)(n & 1023);
          const int h = rem >> 6, d = rem & 63;
          const long idx = (((long)(b * H_ + h)) * S_ + s) * DH_ + d;
          unsigned short bv = f2bf(v);
          if (which == 0) ((unsigned short*)out0)[idx] = bv;
          else if (which == 1) outk[idx] = bv;
          else outv[idx] = bv;
        }
      }
    }
  }
}

// ---- V [bh][s][dh] -> VT [bh][dh][s] ----
__global__ __launch_bounds__(256) void k_tr_v(const unsigned short* __restrict__ v,
                                              unsigned short* __restrict__ vt) {
  __shared__ __align__(16) unsigned short tile[64][72];
  const int bh = blockIdx.y;
  const int s0 = blockIdx.x * 64;
  const int t = threadIdx.x;
  const int r = t >> 2;
  const int c = (t & 3) * 16;
  const unsigned short* src = v + ((long)bh * S_ + s0 + r) * DH_ + c;
  *reinterpret_cast<short8*>(&tile[r][c]) = *reinterpret_cast<const short8*>(src);
  *reinterpret_cast<short8*>(&tile[r][c + 8]) = *reinterpret_cast<const short8*>(src + 8);
  __syncthreads();
  unsigned short* dst = vt + ((long)bh * DH_ + r) * S_ + s0 + c;
#pragma unroll
  for (int jj = 0; jj < 2; jj++) {
    short8 o;
#pragma unroll
    for (int j = 0; j < 8; j++) o[j] = (short)tile[c + jj * 8 + j][r];
    *reinterpret_cast<short8*>(dst + jj * 8) = o;
  }
}

// ---- causal flash attention: 8-warp blocks, in-block KV-split ----
// Block = 512 threads = 2 groups x 4 warps over the SAME 128 q-rows.
// Group g handles kv-tiles t === g (mod 2); per-chunk partials merged in-LDS
// (group1 publishes m/l/bf16-O; group0 combines + stores). Each block serially
// runs chunk pair (pr, 15-pr) -> every block exactly 17 tile-steps, grid 256
// = 1 block/CU, 2 waves/SIMD always resident, uniform load.
// K tile [128][64] swz ^(row&7); V tile [64][128] swz ^(row&15). Dbuf/group.
__global__ __launch_bounds__(512, 2) void k_attn(const unsigned short* __restrict__ qb_,
                                                 const unsigned short* __restrict__ kb,
                                                 const unsigned short* __restrict__ vt,
                                                 unsigned short* __restrict__ attn_out) {
  __shared__ __align__(16) unsigned short lds_k[2][2][8192];  // [grp][buf][128*64]
  __shared__ __align__(16) unsigned short lds_v[2][2][8192];  // [grp][buf][64*128]
  __shared__ float cmb_m[256], cmb_l[256];
  __shared__ unsigned int cmb_o[256][16];  // bf16-packed group1 O-partials

  const int t0_ = threadIdx.x;
  const int w = t0_ >> 6;            // 0..7
  const int grp = w >> 2, wi = w & 3;
  const int l = t0_ & 63;
  const int q32 = l & 31, hi = l >> 5;
  const int r7 = q32 & 7;
  const int r15 = q32 & 15;
  const int lr = l >> 3, sch = (l & 7) ^ lr;   // K staging source chunk
  const int lv4 = l >> 4;                      // V staging row-within-4
  const int slot = wi * 64 + l;

  const int id = blockIdx.x;
  const int xcd = id & 7, sl2 = id >> 3;
  const int bh = 4 * xcd + (sl2 & 3);   // 4 bh per XCD -> ~3MB L2 footprint
  const int pr = sl2 >> 2;              // 0..7: chunk pair (pr, 15-pr)

  const int b = bh >> 4, h = bh & 15;
  const long kvbase = (long)bh * S_ * DH_;
  const long vtbase = (long)bh * DH_ * S_;
  const float SC = 0.125f * LOG2E;  // scores kept in log2 domain

  const unsigned short* kbb = kb + kvbase;
  const unsigned short* vtb = vt + vtbase;

  auto stage = [&](int buf, int kv0) {
#pragma unroll
    for (int i = 0; i < 4; i++) {
      const int R0 = 32 * wi + 8 * i;
      gll16(kbb + (long)(kv0 + R0 + lr) * 64 + sch * 8, &lds_k[grp][buf][R0 * 64]);
      const int V0 = 16 * wi + 4 * i;
      const int svch = (l & 15) ^ (4 * i + lv4);
      gll16(vtb + (long)(V0 + lv4) * S_ + kv0 + svch * 8, &lds_v[grp][buf][V0 * 128]);
    }
  };

#pragma unroll 1
  for (int ch = 0; ch < 2; ch++) {
    const int qc = ch ? (15 - pr) : pr;
    const int ntot = qc + 1;                       // 128-kv tiles in chunk
    const int N = (ntot + 1) >> 1;                 // padded per-group steps
    const int ng = (ntot + (grp == 0 ? 1 : 0)) >> 1;  // grp0 ceil, grp1 floor

    const int q0w = qc * 128 + 32 * wi;
    const int qg = q0w + q32;

    // Q fragments (B-operand): row qg, dh = 16f + 8*hi + j
    short8 qf[4];
#pragma unroll
    for (int f = 0; f < 4; f++)
      qf[f] = *reinterpret_cast<const short8*>(
          qb_ + kvbase + (long)qg * DH_ + 16 * f + 8 * hi);

    f32x16 oacc[2];
#pragma unroll
    for (int dt = 0; dt < 2; dt++)
#pragma unroll
      for (int r = 0; r < 16; r++) oacc[dt][r] = 0.f;
    float m = -1.0e30f, lown = 0.f;

    if (ng > 0) stage(0, grp << 7);
    asm volatile("s_waitcnt vmcnt(0)" ::: "memory");
    __syncthreads();

    for (int s = 0; s < N; s++) {
      const int tile = grp + 2 * s;
      if (s + 1 < ng) stage((s + 1) & 1, (grp + 2 * (s + 1)) << 7);
      if (s < ng) {
        const int kv0 = tile << 7;
        const unsigned short* lk = lds_k[grp][s & 1];
        const unsigned short* lv = lds_v[grp][s & 1];
        const bool diag = (tile == qc);

        // QK^T (swapped): p[16ks+r] = S^T[kv = 32ks + R(r,hi)][q32] * SC
        float p[64];
#pragma unroll
        for (int ks = 0; ks < 4; ks++) {
          f32x16 sa;
#pragma unroll
          for (int r = 0; r < 16; r++) sa[r] = 0.f;
#pragma unroll
          for (int f = 0; f < 4; f++) {
            short8 kf = *reinterpret_cast<const short8*>(
                lk + (32 * ks + q32) * 64 + (((2 * f + hi) ^ r7) << 3));
            sa = __builtin_amdgcn_mfma_f32_32x32x16_bf16(kf, qf[f], sa, 0, 0, 0);
          }
#pragma unroll
          for (int r = 0; r < 16; r++) {
            float s2 = sa[r] * SC;
            if (diag) {
              const int kvg = kv0 + 32 * ks + (r & 3) + 8 * (r >> 2) + 4 * hi;
              if (kvg > qg) s2 = -1.0e30f;
            }
            p[16 * ks + r] = s2;
          }
        }

        // tile max (in-lane tree + lane^32 partner)
        float mx[16];
#pragma unroll
        for (int r = 0; r < 16; r++)
          mx[r] = fmaxf(fmaxf(p[r], p[r + 16]), fmaxf(p[r + 32], p[r + 48]));
#pragma unroll
        for (int st = 8; st >= 1; st >>= 1)
#pragma unroll
          for (int r = 0; r < 8; r++)
            if (r < st) mx[r] = fmaxf(mx[r], mx[r + st]);
        float pmax = fmaxf(mx[0], __shfl_xor(mx[0], 32, 64));

        // defer-max rescale (THR = 8 in log2 domain)
        if (__any(pmax > m + 8.0f)) {
          const float mn = fmaxf(m, pmax);
          const float fsc = exp2f(m - mn);
          m = mn;
          lown *= fsc;
#pragma unroll
          for (int r = 0; r < 16; r++) {
            const int rr = (r & 3) + 8 * (r >> 2) + 4 * hi;
            const float fr = __int_as_float(
                __builtin_amdgcn_ds_bpermute(rr << 2, __float_as_int(fsc)));
            oacc[0][r] *= fr;
            oacc[1][r] *= fr;
          }
        }

        // exp (log2 domain)
#pragma unroll
        for (int i = 0; i < 64; i++) p[i] = exp2f(p[i] - m);

        // own-half row sum
        float sm[16];
#pragma unroll
        for (int r = 0; r < 16; r++)
          sm[r] = (p[r] + p[r + 16]) + (p[r + 32] + p[r + 48]);
#pragma unroll
        for (int st = 8; st >= 1; st >>= 1)
#pragma unroll
          for (int r = 0; r < 8; r++)
            if (r < st) sm[r] += sm[r + st];
        lown += sm[0];

        // PV: 8 k-steps of 16 kv; 2 shfls/step
#pragma unroll
        for (int s4 = 0; s4 < 8; s4++) {
          const int bse = 8 * s4;
          unsigned int t0p = pack_bf(p[bse + 0], p[bse + 1]);
          unsigned int t1p = pack_bf(p[bse + 2], p[bse + 3]);
          unsigned int t2p = pack_bf(p[bse + 4], p[bse + 5]);
          unsigned int t3p = pack_bf(p[bse + 6], p[bse + 7]);
          unsigned int s0 = hi ? t0p : t2p;
          unsigned int s1 = hi ? t1p : t3p;
          unsigned int x0 = __shfl_xor(s0, 32, 64);
          unsigned int x1 = __shfl_xor(s1, 32, 64);
          union { unsigned int u[4]; short8 s8; } pa;
          pa.u[0] = hi ? x0 : t0p;   // kv +{0,1}
          pa.u[1] = hi ? x1 : t1p;   // kv +{2,3}
          pa.u[2] = hi ? t2p : x0;   // kv +{4,5}
          pa.u[3] = hi ? t3p : x1;   // kv +{6,7}
#pragma unroll
          for (int dt = 0; dt < 2; dt++) {
            short8 vf = *reinterpret_cast<const short8*>(
                lv + (32 * dt + q32) * 128 + (((2 * s4 + hi) ^ r15) << 3));
            oacc[dt] = __builtin_amdgcn_mfma_f32_32x32x16_bf16(pa.s8, vf, oacc[dt], 0, 0, 0);
          }
        }
      }
      asm volatile("s_waitcnt vmcnt(0)" ::: "memory");
      __syncthreads();
    }

    // ---- in-LDS combine: group1 publishes, group0 merges + stores ----
    if (grp == 1) {
      const float lt1 = lown + __shfl_xor(lown, 32, 64);
      cmb_m[slot] = m;
      cmb_l[slot] = lt1;
#pragma unroll
      for (int dt = 0; dt < 2; dt++)
#pragma unroll
        for (int i = 0; i < 8; i++)
          cmb_o[slot][dt * 8 + i] = pack_bf(oacc[dt][2 * i], oacc[dt][2 * i + 1]);
    }
    __syncthreads();
    if (grp == 0) {
      const float lt0 = lown + __shfl_xor(lown, 32, 64);
      const float m1 = cmb_m[slot], l1c = cmb_l[slot];
      const float ms = fmaxf(m, m1);
      const float w0 = exp2f(m - ms), w1 = exp2f(m1 - ms);
      const float linv = 1.0f / (w0 * lt0 + w1 * l1c);
#pragma unroll
      for (int r = 0; r < 16; r++) {
        const int rr = (r & 3) + 8 * (r >> 2) + 4 * hi;
        const float w0r = __int_as_float(
            __builtin_amdgcn_ds_bpermute(rr << 2, __float_as_int(w0)));
        const float w1r = __int_as_float(
            __builtin_amdgcn_ds_bpermute(rr << 2, __float_as_int(w1)));
        const float lir = __int_as_float(
            __builtin_amdgcn_ds_bpermute(rr << 2, __float_as_int(linv)));
        const long row = (long)b * S_ + q0w + rr;
#pragma unroll
        for (int dt = 0; dt < 2; dt++) {
          const unsigned int wd = cmb_o[slot][dt * 8 + (r >> 1)];
          const float o1 = bf2f((unsigned short)((r & 1) ? (wd >> 16) : (wd & 0xffffu)));
          attn_out[row * (H_ * DH_) + h * DH_ + 32 * dt + q32] =
              f2bf((w0r * oacc[dt][r] + w1r * o1) * lir);
        }
      }
    }
    __syncthreads();
  }
}

extern "C" void kernel_launch(void* const* d_in, const int* in_sizes, int n_in,
                              void* d_out, int out_size, void* d_ws, size_t ws_size,
                              hipStream_t stream) {
  (void)in_sizes; (void)n_in; (void)out_size; (void)ws_size;
  const float* hs    = (const float*)d_in[0];
  // d_in[1] = attention_mask: deterministic causal tril, applied analytically.
  const float* Wqkv  = (const float*)d_in[2];
  const float* bqkv  = (const float*)d_in[3];
  const float* Wproj = (const float*)d_in[4];
  const float* bproj = (const float*)d_in[5];
  float* out = (float*)d_out;

  unsigned short* ws    = (unsigned short*)d_ws;
  unsigned short* hid   = ws;                 // 4096*1024
  unsigned short* wqkvT = hid + 4194304;      // 3072*1024
  unsigned short* wprT  = wqkvT + 3145728;    // 1024*1024
  unsigned short* q_b   = wprT + 1048576;     // [bh][s][dh]
  unsigned short* k_b   = q_b + 4194304;
  unsigned short* v_b   = k_b + 4194304;
  unsigned short* vt_b  = v_b + 4194304;      // [bh][dh][s]
  unsigned short* ao    = vt_b + 4194304;     // [b*s][H*DH]

  k_prep<<<8192, 256, 0, stream>>>(hs, Wqkv, Wproj, hid, wqkvT, wprT);
  k_gemm<0, 128><<<dim3(32, 24), 256, 0, stream>>>(hid, wqkvT, bqkv, (void*)q_b, k_b, v_b,
                                                   4096, 3072, 1024);
  k_tr_v<<<dim3(32, 32), 256, 0, stream>>>(v_b, vt_b);
  k_attn<<<256, 512, 0, stream>>>(q_b, k_b, vt_b, ao);
  k_gemm<1, 64><<<dim3(32, 16), 256, 0, stream>>>(ao, wprT, bproj, (void*)out, nullptr, nullptr,
                                                  4096, 1024, 1024);
}